// Round 1
// baseline (2356.100 us; speedup 1.0000x reference)
//
#include <hip/hip_runtime.h>

#define B_DIM 32
#define C_DIM 512
#define N_SP 1024      // H*W
#define GROUPS 32
#define CPG 16         // channels per group
#define EPS 1e-5f

// ---------------- GroupNorm stats: one block per (b,g) ----------------
__global__ __launch_bounds__(256) void gn_stats_kernel(const float* __restrict__ x,
                                                       float* __restrict__ stats) {
    int bg = blockIdx.x;                       // b*GROUPS + g
    const float4* p4 = (const float4*)(x + (size_t)bg * (CPG * N_SP));
    int tid = threadIdx.x;
    float s = 0.f, sq = 0.f;
    for (int i = tid; i < (CPG * N_SP) / 4; i += 256) {
        float4 v = p4[i];
        s  += v.x + v.y + v.z + v.w;
        sq += v.x * v.x + v.y * v.y + v.z * v.z + v.w * v.w;
    }
    for (int off = 32; off > 0; off >>= 1) {
        s  += __shfl_xor(s, off);
        sq += __shfl_xor(sq, off);
    }
    __shared__ float ls[4], lq[4];
    int wid = tid >> 6;
    if ((tid & 63) == 0) { ls[wid] = s; lq[wid] = sq; }
    __syncthreads();
    if (tid == 0) {
        s  = ls[0] + ls[1] + ls[2] + ls[3];
        sq = lq[0] + lq[1] + lq[2] + lq[3];
        float mean = s / (float)(CPG * N_SP);
        float var  = sq / (float)(CPG * N_SP) - mean * mean;
        stats[2 * bg]     = mean;
        stats[2 * bg + 1] = rsqrtf(var + EPS);
    }
}

// ---------------- GroupNorm apply (elementwise) ----------------
__global__ __launch_bounds__(256) void gn_apply_kernel(const float* __restrict__ x,
                                                       const float* __restrict__ stats,
                                                       const float* __restrict__ w,
                                                       const float* __restrict__ b,
                                                       float* __restrict__ h) {
    size_t i4 = (size_t)blockIdx.x * blockDim.x + threadIdx.x;   // float4 index
    size_t total4 = (size_t)B_DIM * C_DIM * N_SP / 4;
    if (i4 >= total4) return;
    size_t idx = i4 * 4;
    int c  = (int)((idx / N_SP) % C_DIM);
    int bg = (int)(idx / ((size_t)CPG * N_SP));
    float mean = stats[2 * bg], rstd = stats[2 * bg + 1];
    float sw = w[c] * rstd;
    float sb = b[c] - mean * sw;
    float4 v = ((const float4*)x)[i4];
    float4 o;
    o.x = v.x * sw + sb; o.y = v.y * sw + sb;
    o.z = v.z * sw + sb; o.w = v.w * sw + sb;
    ((float4*)h)[i4] = o;
}

// ---------------- GEMM variant A: Y[b] = W(MxK) * X[b](KxN) + bias (+resid) ----
// M=512, N=1024, K=512. BM=BN=64, BK=16, 256 thr, 4x4 per thread.
template <bool RESID>
__global__ __launch_bounds__(256) void gemm_wx_kernel(const float* __restrict__ W,
                                                      const float* __restrict__ X,
                                                      const float* __restrict__ bias,
                                                      const float* __restrict__ resid,
                                                      float* __restrict__ Y) {
    const int M = C_DIM, N = N_SP, K = C_DIM;
    int bz = blockIdx.z;
    const float* Xb = X + (size_t)bz * K * N;
    float* Yb = Y + (size_t)bz * M * N;
    const float* Rb = RESID ? (resid + (size_t)bz * M * N) : nullptr;
    int bm = blockIdx.y * 64, bn = blockIdx.x * 64;

    __shared__ float As[16][68];   // [k][m], padded
    __shared__ float Bs[16][64];   // [k][n]
    int tid = threadIdx.x;
    int tm = tid >> 4, tn = tid & 15;
    float acc[4][4] = {};

    for (int kt = 0; kt < K; kt += 16) {
        {   // A tile: W[bm+r][kt+c4..+3], transpose into As
            int r = tid >> 2, c4 = (tid & 3) * 4;
            float4 a = *(const float4*)&W[(size_t)(bm + r) * K + kt + c4];
            As[c4 + 0][r] = a.x; As[c4 + 1][r] = a.y;
            As[c4 + 2][r] = a.z; As[c4 + 3][r] = a.w;
        }
        {   // B tile: X[kt+c][bn+n4..+3]
            int c = tid >> 4, n4 = (tid & 15) * 4;
            *(float4*)&Bs[c][n4] = *(const float4*)&Xb[(size_t)(kt + c) * N + bn + n4];
        }
        __syncthreads();
#pragma unroll
        for (int k = 0; k < 16; ++k) {
            float a[4], bb[4];
#pragma unroll
            for (int i = 0; i < 4; ++i) a[i] = As[k][tm + 16 * i];
#pragma unroll
            for (int j = 0; j < 4; ++j) bb[j] = Bs[k][tn + 16 * j];
#pragma unroll
            for (int i = 0; i < 4; ++i)
#pragma unroll
                for (int j = 0; j < 4; ++j) acc[i][j] += a[i] * bb[j];
        }
        __syncthreads();
    }
#pragma unroll
    for (int i = 0; i < 4; ++i) {
        int row = bm + tm + 16 * i;
        float bv = bias[row];
#pragma unroll
        for (int j = 0; j < 4; ++j) {
            int col = bn + tn + 16 * j;
            float v = acc[i][j] + bv;
            if (RESID) v += Rb[(size_t)row * N + col];
            Yb[(size_t)row * N + col] = v;
        }
    }
}

// ---------------- Scores: S[b,i,j] = scale * sum_c Q[b,c,i] * K[b,c,j] ----------
__global__ __launch_bounds__(256) void scores_kernel(const float* __restrict__ Q,
                                                     const float* __restrict__ Kk,
                                                     float* __restrict__ S, int b0) {
    const int N = N_SP, Kd = C_DIM;
    int b = b0 + blockIdx.z;
    const float* Qb = Q + (size_t)b * Kd * N;
    const float* Kb = Kk + (size_t)b * Kd * N;
    float* Sb = S + (size_t)blockIdx.z * N * N;
    int bm = blockIdx.y * 64, bn = blockIdx.x * 64;

    __shared__ float As[16][64];   // [k][i]
    __shared__ float Bs[16][64];   // [k][j]
    int tid = threadIdx.x;
    int tm = tid >> 4, tn = tid & 15;
    float acc[4][4] = {};

    for (int kt = 0; kt < Kd; kt += 16) {
        int c = tid >> 4, i4 = (tid & 15) * 4;
        *(float4*)&As[c][i4] = *(const float4*)&Qb[(size_t)(kt + c) * N + bm + i4];
        *(float4*)&Bs[c][i4] = *(const float4*)&Kb[(size_t)(kt + c) * N + bn + i4];
        __syncthreads();
#pragma unroll
        for (int k = 0; k < 16; ++k) {
            float a[4], bb[4];
#pragma unroll
            for (int i = 0; i < 4; ++i) a[i] = As[k][tm + 16 * i];
#pragma unroll
            for (int j = 0; j < 4; ++j) bb[j] = Bs[k][tn + 16 * j];
#pragma unroll
            for (int i = 0; i < 4; ++i)
#pragma unroll
                for (int j = 0; j < 4; ++j) acc[i][j] += a[i] * bb[j];
        }
        __syncthreads();
    }
    const float scale = 0.044194173824159216f;   // 512^-0.5
#pragma unroll
    for (int i = 0; i < 4; ++i)
#pragma unroll
        for (int j = 0; j < 4; ++j)
            Sb[(size_t)(bm + tm + 16 * i) * N + bn + tn + 16 * j] = acc[i][j] * scale;
}

// ---------------- Softmax over last dim, in place; one block per row ----------
__global__ __launch_bounds__(256) void softmax_kernel(float* __restrict__ S) {
    size_t row = blockIdx.x;
    float* p = S + row * N_SP;
    int tid = threadIdx.x;
    float4 v = ((float4*)p)[tid];
    float m = fmaxf(fmaxf(v.x, v.y), fmaxf(v.z, v.w));
    for (int off = 32; off > 0; off >>= 1) m = fmaxf(m, __shfl_xor(m, off));
    __shared__ float lm[4], lsum[4];
    int wid = tid >> 6;
    if ((tid & 63) == 0) lm[wid] = m;
    __syncthreads();
    m = fmaxf(fmaxf(lm[0], lm[1]), fmaxf(lm[2], lm[3]));
    v.x = __expf(v.x - m); v.y = __expf(v.y - m);
    v.z = __expf(v.z - m); v.w = __expf(v.w - m);
    float s = v.x + v.y + v.z + v.w;
    for (int off = 32; off > 0; off >>= 1) s += __shfl_xor(s, off);
    if ((tid & 63) == 0) lsum[wid] = s;
    __syncthreads();
    s = lsum[0] + lsum[1] + lsum[2] + lsum[3];
    float inv = 1.f / s;
    v.x *= inv; v.y *= inv; v.z *= inv; v.w *= inv;
    ((float4*)p)[tid] = v;
}

// ---------------- AV: O[b,c,i] = sum_j V[b,c,j] * A[b,i,j] ----------------
__global__ __launch_bounds__(256) void av_kernel(const float* __restrict__ V,
                                                 const float* __restrict__ S,
                                                 float* __restrict__ O, int b0) {
    int b = b0 + blockIdx.z;
    const float* Vb = V + (size_t)b * C_DIM * N_SP;
    const float* Sb = S + (size_t)blockIdx.z * N_SP * N_SP;
    float* Ob = O + (size_t)b * C_DIM * N_SP;
    int bm = blockIdx.y * 64, bn = blockIdx.x * 64;

    __shared__ float As[16][68];   // [j][c]
    __shared__ float Bs[16][68];   // [j][i]
    int tid = threadIdx.x;
    int tm = tid >> 4, tn = tid & 15;
    float acc[4][4] = {};

    for (int kt = 0; kt < N_SP; kt += 16) {
        int r = tid >> 2, j4 = (tid & 3) * 4;
        {   // V[bm+r][kt+j4..]
            float4 a = *(const float4*)&Vb[(size_t)(bm + r) * N_SP + kt + j4];
            As[j4 + 0][r] = a.x; As[j4 + 1][r] = a.y;
            As[j4 + 2][r] = a.z; As[j4 + 3][r] = a.w;
        }
        {   // S[bn+r][kt+j4..]
            float4 a = *(const float4*)&Sb[(size_t)(bn + r) * N_SP + kt + j4];
            Bs[j4 + 0][r] = a.x; Bs[j4 + 1][r] = a.y;
            Bs[j4 + 2][r] = a.z; Bs[j4 + 3][r] = a.w;
        }
        __syncthreads();
#pragma unroll
        for (int k = 0; k < 16; ++k) {
            float a[4], bb[4];
#pragma unroll
            for (int i = 0; i < 4; ++i) a[i] = As[k][tm + 16 * i];
#pragma unroll
            for (int j = 0; j < 4; ++j) bb[j] = Bs[k][tn + 16 * j];
#pragma unroll
            for (int i = 0; i < 4; ++i)
#pragma unroll
                for (int j = 0; j < 4; ++j) acc[i][j] += a[i] * bb[j];
        }
        __syncthreads();
    }
#pragma unroll
    for (int i = 0; i < 4; ++i)
#pragma unroll
        for (int j = 0; j < 4; ++j)
            Ob[(size_t)(bm + tm + 16 * i) * N_SP + bn + tn + 16 * j] = acc[i][j];
}

extern "C" void kernel_launch(void* const* d_in, const int* in_sizes, int n_in,
                              void* d_out, int out_size, void* d_ws, size_t ws_size,
                              hipStream_t stream) {
    const float* x      = (const float*)d_in[0];
    const float* norm_w = (const float*)d_in[1];
    const float* norm_b = (const float*)d_in[2];
    const float* q_w    = (const float*)d_in[3];
    const float* q_b    = (const float*)d_in[4];
    const float* k_w    = (const float*)d_in[5];
    const float* k_b    = (const float*)d_in[6];
    const float* v_w    = (const float*)d_in[7];
    const float* v_b    = (const float*)d_in[8];
    const float* proj_w = (const float*)d_in[9];
    const float* proj_b = (const float*)d_in[10];
    float* out = (float*)d_out;

    const size_t TENS = (size_t)B_DIM * C_DIM * N_SP;   // 16,777,216 floats
    float* h     = (float*)d_ws;
    float* q     = h + TENS;
    float* k     = q + TENS;
    float* stats = k + TENS;            // 2048 floats
    float* attn  = stats + 4096;        // chunked [nb,1024,1024]
    float* v     = out;                 // d_out doubles as V until final write
    float* h2    = h;                   // attention output reuses h

    size_t used_bytes = ((size_t)3 * TENS + 4096) * sizeof(float);
    size_t avail = ws_size > used_bytes ? ws_size - used_bytes : 0;
    int chunk = (int)(avail / ((size_t)N_SP * N_SP * sizeof(float)));
    if (chunk > B_DIM) chunk = B_DIM;
    if (chunk < 1) chunk = 1;

    gn_stats_kernel<<<B_DIM * GROUPS, 256, 0, stream>>>(x, stats);
    gn_apply_kernel<<<(int)(TENS / 4 / 256), 256, 0, stream>>>(x, stats, norm_w, norm_b, h);

    dim3 gproj(N_SP / 64, C_DIM / 64, B_DIM);
    gemm_wx_kernel<false><<<gproj, 256, 0, stream>>>(q_w, h, q_b, nullptr, q);
    gemm_wx_kernel<false><<<gproj, 256, 0, stream>>>(k_w, h, k_b, nullptr, k);
    gemm_wx_kernel<false><<<gproj, 256, 0, stream>>>(v_w, h, v_b, nullptr, v);

    for (int b0 = 0; b0 < B_DIM; b0 += chunk) {
        int nb = (b0 + chunk <= B_DIM) ? chunk : (B_DIM - b0);
        dim3 gs(N_SP / 64, N_SP / 64, nb);
        scores_kernel<<<gs, 256, 0, stream>>>(q, k, attn, b0);
        softmax_kernel<<<nb * N_SP, 256, 0, stream>>>(attn);
        dim3 ga(N_SP / 64, C_DIM / 64, nb);
        av_kernel<<<ga, 256, 0, stream>>>(v, attn, h2, b0);
    }

    gemm_wx_kernel<true><<<gproj, 256, 0, stream>>>(proj_w, h2, proj_b, x, out);
}

// Round 2
// 345.638 us; speedup vs baseline: 6.8167x; 6.8167x over previous
//
#include <hip/hip_runtime.h>
#include <cstdint>

#define B_DIM 32
#define C_DIM 512
#define N_SP 1024
#define GROUPS 32
#define CPG 16
#define EPS 1e-5f

typedef __attribute__((ext_vector_type(8))) __bf16 bf16x8;
typedef __attribute__((ext_vector_type(4))) __bf16 bf16x4;
typedef __attribute__((ext_vector_type(4))) float f32x4;

// async global->LDS, 16B per lane. LDS dest = wave-uniform base + lane*16.
__device__ __forceinline__ void gload16(const void* g, void* l) {
    __builtin_amdgcn_global_load_lds(
        (__attribute__((address_space(1))) void*)(unsigned long long)(uintptr_t)g,
        (__attribute__((address_space(3))) void*)(unsigned int)(uintptr_t)l,
        16, 0, 0);
}

// ---------------- GroupNorm stats ----------------
__global__ __launch_bounds__(256) void gn_stats_kernel(const float* __restrict__ x,
                                                       float* __restrict__ stats) {
    int bg = blockIdx.x;
    const float4* p4 = (const float4*)(x + (size_t)bg * (CPG * N_SP));
    int tid = threadIdx.x;
    float s = 0.f, sq = 0.f;
    for (int i = tid; i < (CPG * N_SP) / 4; i += 256) {
        float4 v = p4[i];
        s  += v.x + v.y + v.z + v.w;
        sq += v.x * v.x + v.y * v.y + v.z * v.z + v.w * v.w;
    }
    for (int off = 32; off > 0; off >>= 1) {
        s  += __shfl_xor(s, off);
        sq += __shfl_xor(sq, off);
    }
    __shared__ float ls[4], lq[4];
    int wid = tid >> 6;
    if ((tid & 63) == 0) { ls[wid] = s; lq[wid] = sq; }
    __syncthreads();
    if (tid == 0) {
        s  = ls[0] + ls[1] + ls[2] + ls[3];
        sq = lq[0] + lq[1] + lq[2] + lq[3];
        float mean = s / (float)(CPG * N_SP);
        float var  = sq / (float)(CPG * N_SP) - mean * mean;
        stats[2 * bg]     = mean;
        stats[2 * bg + 1] = rsqrtf(var + EPS);
    }
}

// ------- GroupNorm apply + transpose: x[b][c][n] -> hT[b][n][c] (bf16) -------
__global__ __launch_bounds__(256) void gn_apply_t_kernel(const float* __restrict__ x,
                                                         const float* __restrict__ stats,
                                                         const float* __restrict__ w,
                                                         const float* __restrict__ b,
                                                         __bf16* __restrict__ hT) {
    int bn = blockIdx.x * 64, bc = blockIdx.y * 64, bb = blockIdx.z;
    __shared__ float tile[64][65];
    __shared__ float sw[64], sb[64];
    int t = threadIdx.x;
    if (t < 64) {
        int c = bc + t;
        int g = c / CPG;
        float mean = stats[2 * (bb * GROUPS + g)];
        float rstd = stats[2 * (bb * GROUPS + g) + 1];
        float s = w[c] * rstd;
        sw[t] = s;
        sb[t] = b[c] - mean * s;
    }
    __syncthreads();
    const float* xb = x + ((size_t)bb * C_DIM + bc) * N_SP + bn;
#pragma unroll
    for (int it = 0; it < 4; ++it) {
        int cl = (t >> 4) + 16 * it;
        int n4 = (t & 15) * 4;
        float4 v = *(const float4*)&xb[(size_t)cl * N_SP + n4];
        float s = sw[cl], o = sb[cl];
        tile[cl][n4 + 0] = v.x * s + o;
        tile[cl][n4 + 1] = v.y * s + o;
        tile[cl][n4 + 2] = v.z * s + o;
        tile[cl][n4 + 3] = v.w * s + o;
    }
    __syncthreads();
    __bf16* hb = hT + ((size_t)bb * N_SP + bn) * C_DIM + bc;
    int nl = t >> 2, c16 = (t & 3) * 16;
    bf16x8 o1, o2;
#pragma unroll
    for (int e = 0; e < 8; ++e) o1[e] = (__bf16)tile[c16 + e][nl];
#pragma unroll
    for (int e = 0; e < 8; ++e) o2[e] = (__bf16)tile[c16 + 8 + e][nl];
    *(bf16x8*)&hb[(size_t)nl * C_DIM + c16] = o1;
    *(bf16x8*)&hb[(size_t)nl * C_DIM + c16 + 8] = o2;
}

// ---------------- fp32 -> bf16 weight conversion ----------------
__global__ __launch_bounds__(256) void f2bf_kernel(const float* __restrict__ in,
                                                   __bf16* __restrict__ out) {
    int i = blockIdx.x * 256 + threadIdx.x;
    float4 v = ((const float4*)in)[i];
    bf16x4 o;
    o[0] = (__bf16)v.x; o[1] = (__bf16)v.y; o[2] = (__bf16)v.z; o[3] = (__bf16)v.w;
    ((bf16x4*)out)[i] = o;
}

// ---------------- bf16 MFMA GEMM: C[M][N] = A[M][K(ldA)] * BT[N][K]^T ----------------
// EPI: 0 = bf16 out; 1 = bf16 out + bias[col]; 2 = bf16 out + bias[row];
//      3 = f32 out * scale; 4 = f32 out + bias[row] + resid
template <int M, int N, int K, int LDA, int EPI>
__global__ __launch_bounds__(256) void gemm_bt(const __bf16* __restrict__ A, size_t sA,
                                               const __bf16* __restrict__ BT, size_t sB,
                                               void* __restrict__ Y, size_t sY,
                                               const float* __restrict__ bias,
                                               const float* __restrict__ resid, size_t sR,
                                               float scale) {
    __shared__ __align__(16) __bf16 As[128 * 32];
    __shared__ __align__(16) __bf16 Bs[128 * 32];

    const int tid = threadIdx.x;
    const int bm = blockIdx.y * 128, bn = blockIdx.x * 128;
    const int bz = blockIdx.z;
    const __bf16* Ab = A + (size_t)bz * sA;
    const __bf16* Bb = BT + (size_t)bz * sB;

    // staging addresses: linear LDS [row][k], 64B per row (32 bf16), 2 chunks of 4KB
    const int o0 = tid * 16;
    const int o1 = o0 + 4096;
    const __bf16* aSrc0 = Ab + (size_t)(bm + (o0 >> 6)) * LDA + ((o0 & 63) >> 1);
    const __bf16* aSrc1 = Ab + (size_t)(bm + (o1 >> 6)) * LDA + ((o1 & 63) >> 1);
    const __bf16* bSrc0 = Bb + (size_t)(bn + (o0 >> 6)) * K + ((o0 & 63) >> 1);
    const __bf16* bSrc1 = Bb + (size_t)(bn + (o1 >> 6)) * K + ((o1 & 63) >> 1);
    const int wv_ = tid >> 6;
    __bf16* aDst0 = &As[wv_ * 512];
    __bf16* aDst1 = &As[2048 + wv_ * 512];
    __bf16* bDst0 = &Bs[wv_ * 512];
    __bf16* bDst1 = &Bs[2048 + wv_ * 512];

    const int lane = tid & 63;
    const int wr = wv_ >> 1, wc = wv_ & 1;
    const int lrow = lane & 15, koct = lane >> 4;
    const __bf16* aBase = &As[(size_t)(wr * 64 + lrow) * 32 + koct * 8];
    const __bf16* bBase = &Bs[(size_t)(wc * 64 + lrow) * 32 + koct * 8];

    f32x4 zero = {0.f, 0.f, 0.f, 0.f};
    f32x4 acc[4][4];
#pragma unroll
    for (int i = 0; i < 4; ++i)
#pragma unroll
        for (int j = 0; j < 4; ++j) acc[i][j] = zero;

    for (int kt = 0; kt < K; kt += 32) {
        gload16(aSrc0 + kt, aDst0);
        gload16(aSrc1 + kt, aDst1);
        gload16(bSrc0 + kt, bDst0);
        gload16(bSrc1 + kt, bDst1);
        __syncthreads();   // compiler drains vmcnt before s_barrier
        bf16x8 af[4], bfr[4];
#pragma unroll
        for (int i = 0; i < 4; ++i) af[i] = *(const bf16x8*)(aBase + i * 16 * 32);
#pragma unroll
        for (int j = 0; j < 4; ++j) bfr[j] = *(const bf16x8*)(bBase + j * 16 * 32);
#pragma unroll
        for (int i = 0; i < 4; ++i)
#pragma unroll
            for (int j = 0; j < 4; ++j)
                acc[i][j] = __builtin_amdgcn_mfma_f32_16x16x32_bf16(af[i], bfr[j], acc[i][j], 0, 0, 0);
        __syncthreads();
    }

    // C/D layout: col = lane&15, row = (lane>>4)*4 + reg
    const int lr4 = (lane >> 4) * 4;
    float* Yf = (float*)Y + (size_t)bz * sY;
    __bf16* Yh = (__bf16*)Y + (size_t)bz * sY;
    const float* Rb = (EPI == 4) ? (resid + (size_t)bz * sR) : nullptr;
#pragma unroll
    for (int i = 0; i < 4; ++i) {
#pragma unroll
        for (int r = 0; r < 4; ++r) {
            int grow = bm + wr * 64 + i * 16 + lr4 + r;
            float bm_ = (EPI == 2 || EPI == 4) ? bias[grow] : 0.f;
#pragma unroll
            for (int j = 0; j < 4; ++j) {
                int gcol = bn + wc * 64 + j * 16 + lrow;
                float vv = acc[i][j][r];
                if (EPI == 1) vv += bias[gcol];
                if (EPI == 2 || EPI == 4) vv += bm_;
                if (EPI == 3) vv *= scale;
                size_t yi = (size_t)grow * N + gcol;
                if (EPI == 3 || EPI == 4) {
                    float o = vv;
                    if (EPI == 4) o += Rb[yi];
                    Yf[yi] = o;
                } else {
                    Yh[yi] = (__bf16)vv;
                }
            }
        }
    }
}

// ------- softmax over row of 1024 fp32, write bf16 P packed in-place -------
__global__ __launch_bounds__(256) void softmax_kernel(float* __restrict__ S) {
    float* p = S + (size_t)blockIdx.x * N_SP;
    int tid = threadIdx.x;
    float4 v = ((float4*)p)[tid];
    float m = fmaxf(fmaxf(v.x, v.y), fmaxf(v.z, v.w));
    for (int off = 32; off > 0; off >>= 1) m = fmaxf(m, __shfl_xor(m, off));
    __shared__ float lm[4], lsum[4];
    int wid = tid >> 6;
    if ((tid & 63) == 0) lm[wid] = m;
    __syncthreads();
    m = fmaxf(fmaxf(lm[0], lm[1]), fmaxf(lm[2], lm[3]));
    v.x = __expf(v.x - m); v.y = __expf(v.y - m);
    v.z = __expf(v.z - m); v.w = __expf(v.w - m);
    float s = v.x + v.y + v.z + v.w;
    for (int off = 32; off > 0; off >>= 1) s += __shfl_xor(s, off);
    if ((tid & 63) == 0) lsum[wid] = s;
    __syncthreads();
    s = lsum[0] + lsum[1] + lsum[2] + lsum[3];
    float inv = 1.f / s;
    bf16x4 o;
    o[0] = (__bf16)(v.x * inv); o[1] = (__bf16)(v.y * inv);
    o[2] = (__bf16)(v.z * inv); o[3] = (__bf16)(v.w * inv);
    __syncthreads();                 // all float4 reads of this row are done
    ((bf16x4*)p)[tid] = o;           // first 2048 bytes of the 4096B row
}

extern "C" void kernel_launch(void* const* d_in, const int* in_sizes, int n_in,
                              void* d_out, int out_size, void* d_ws, size_t ws_size,
                              hipStream_t stream) {
    const float* x      = (const float*)d_in[0];
    const float* norm_w = (const float*)d_in[1];
    const float* norm_b = (const float*)d_in[2];
    const float* q_w    = (const float*)d_in[3];
    const float* q_b    = (const float*)d_in[4];
    const float* k_w    = (const float*)d_in[5];
    const float* k_b    = (const float*)d_in[6];
    const float* v_w    = (const float*)d_in[7];
    const float* v_b    = (const float*)d_in[8];
    const float* proj_w = (const float*)d_in[9];
    const float* proj_b = (const float*)d_in[10];
    float* out = (float*)d_out;

    const size_t ELEM = (size_t)N_SP * C_DIM;          // 524288
    char* ws = (char*)d_ws;
    __bf16* hT = (__bf16*)ws;                          // 32MB; reused as Ot
    __bf16* qT = (__bf16*)(ws + ((size_t)32 << 20));   // 32MB
    __bf16* kT = (__bf16*)(ws + ((size_t)64 << 20));   // 32MB
    __bf16* wq = (__bf16*)(ws + ((size_t)96 << 20));
    __bf16* wk = wq + 262144;
    __bf16* wv = wk + 262144;
    __bf16* wp = wv + 262144;
    float* stats = (float*)(ws + ((size_t)98 << 20));
    size_t sbase = ((size_t)98 << 20) + 65536;
    float* S = (float*)(ws + sbase);
    __bf16* v  = (__bf16*)d_out;                       // V lives in d_out until proj
    __bf16* Ot = hT;                                   // hT dead after v GEMM

    int chunk = (int)((ws_size - sbase) >> 22);        // 4MB per batch of S
    if (chunk > B_DIM) chunk = B_DIM;
    if (chunk < 1) chunk = 1;

    gn_stats_kernel<<<B_DIM * GROUPS, 256, 0, stream>>>(x, stats);
    gn_apply_t_kernel<<<dim3(16, 8, B_DIM), 256, 0, stream>>>(x, stats, norm_w, norm_b, hT);

    f2bf_kernel<<<256, 256, 0, stream>>>(q_w, wq);
    f2bf_kernel<<<256, 256, 0, stream>>>(k_w, wk);
    f2bf_kernel<<<256, 256, 0, stream>>>(v_w, wv);
    f2bf_kernel<<<256, 256, 0, stream>>>(proj_w, wp);

    // qT[n][oc] = sum_c hT[n][c] * wq[oc][c] + q_b[oc]
    gemm_bt<1024, 512, 512, 512, 1><<<dim3(4, 8, B_DIM), 256, 0, stream>>>(
        hT, ELEM, wq, 0, qT, ELEM, q_b, nullptr, 0, 1.f);
    gemm_bt<1024, 512, 512, 512, 1><<<dim3(4, 8, B_DIM), 256, 0, stream>>>(
        hT, ELEM, wk, 0, kT, ELEM, k_b, nullptr, 0, 1.f);
    // v[oc][n] = sum_c wv[oc][c] * hT[n][c] + v_b[oc]
    gemm_bt<512, 1024, 512, 512, 2><<<dim3(8, 4, B_DIM), 256, 0, stream>>>(
        wv, 0, hT, ELEM, v, ELEM, v_b, nullptr, 0, 1.f);

    const float scale = 0.044194173824159216f;  // 512^-0.5
    for (int b0 = 0; b0 < B_DIM; b0 += chunk) {
        int nb = (b0 + chunk <= B_DIM) ? chunk : (B_DIM - b0);
        // S[i][j] = scale * sum_c qT[i][c] kT[j][c]
        gemm_bt<1024, 1024, 512, 512, 3><<<dim3(8, 8, nb), 256, 0, stream>>>(
            qT + (size_t)b0 * ELEM, ELEM, kT + (size_t)b0 * ELEM, ELEM,
            S, (size_t)N_SP * N_SP, nullptr, nullptr, 0, scale);
        softmax_kernel<<<nb * N_SP, 256, 0, stream>>>(S);
        // Ot[i][c] = sum_j P[i][j] v[c][j]   (P packed bf16 in S rows, ld 2048)
        gemm_bt<1024, 512, 1024, 2048, 0><<<dim3(4, 8, nb), 256, 0, stream>>>(
            (const __bf16*)S, (size_t)N_SP * 2048, v + (size_t)b0 * ELEM, ELEM,
            Ot + (size_t)b0 * ELEM, ELEM, nullptr, nullptr, 0, 1.f);
    }

    // out[oc][n] = sum_c wp[oc][c] Ot[n][c] + proj_b[oc] + x[oc][n]
    gemm_bt<512, 1024, 512, 512, 4><<<dim3(8, 4, B_DIM), 256, 0, stream>>>(
        wp, 0, Ot, ELEM, out, ELEM, proj_b, x, ELEM, 1.f);
}

// Round 3
// 287.372 us; speedup vs baseline: 8.1988x; 1.2028x over previous
//
#include <hip/hip_runtime.h>
#include <cstdint>

#define B_DIM 32
#define C_DIM 512
#define N_SP 1024
#define GROUPS 32
#define CPG 16
#define EPS 1e-5f

typedef __attribute__((ext_vector_type(8))) __bf16 bf16x8;
typedef __attribute__((ext_vector_type(4))) __bf16 bf16x4;
typedef __attribute__((ext_vector_type(4))) float f32x4;

// async global->LDS, 16B per lane. LDS dest = wave-uniform base + lane*16.
__device__ __forceinline__ void gload16(const void* g, void* l) {
    __builtin_amdgcn_global_load_lds(
        (__attribute__((address_space(1))) void*)(unsigned long long)(uintptr_t)g,
        (__attribute__((address_space(3))) void*)(unsigned int)(uintptr_t)l,
        16, 0, 0);
}

// ---------------- GroupNorm stats ----------------
__global__ __launch_bounds__(256) void gn_stats_kernel(const float* __restrict__ x,
                                                       float* __restrict__ stats) {
    int bg = blockIdx.x;
    const float4* p4 = (const float4*)(x + (size_t)bg * (CPG * N_SP));
    int tid = threadIdx.x;
    float s = 0.f, sq = 0.f;
    for (int i = tid; i < (CPG * N_SP) / 4; i += 256) {
        float4 v = p4[i];
        s  += v.x + v.y + v.z + v.w;
        sq += v.x * v.x + v.y * v.y + v.z * v.z + v.w * v.w;
    }
    for (int off = 32; off > 0; off >>= 1) {
        s  += __shfl_xor(s, off);
        sq += __shfl_xor(sq, off);
    }
    __shared__ float ls[4], lq[4];
    int wid = tid >> 6;
    if ((tid & 63) == 0) { ls[wid] = s; lq[wid] = sq; }
    __syncthreads();
    if (tid == 0) {
        s  = ls[0] + ls[1] + ls[2] + ls[3];
        sq = lq[0] + lq[1] + lq[2] + lq[3];
        float mean = s / (float)(CPG * N_SP);
        float var  = sq / (float)(CPG * N_SP) - mean * mean;
        stats[2 * bg]     = mean;
        stats[2 * bg + 1] = rsqrtf(var + EPS);
    }
}

// ------- GroupNorm apply + transpose: x[b][c][n] -> hT[b][n][c] (bf16) -------
__global__ __launch_bounds__(256) void gn_apply_t_kernel(const float* __restrict__ x,
                                                         const float* __restrict__ stats,
                                                         const float* __restrict__ w,
                                                         const float* __restrict__ b,
                                                         __bf16* __restrict__ hT) {
    int bn = blockIdx.x * 64, bc = blockIdx.y * 64, bb = blockIdx.z;
    __shared__ float tile[64][65];
    __shared__ float sw[64], sb[64];
    int t = threadIdx.x;
    if (t < 64) {
        int c = bc + t;
        int g = c / CPG;
        float mean = stats[2 * (bb * GROUPS + g)];
        float rstd = stats[2 * (bb * GROUPS + g) + 1];
        float s = w[c] * rstd;
        sw[t] = s;
        sb[t] = b[c] - mean * s;
    }
    __syncthreads();
    const float* xb = x + ((size_t)bb * C_DIM + bc) * N_SP + bn;
#pragma unroll
    for (int it = 0; it < 4; ++it) {
        int cl = (t >> 4) + 16 * it;
        int n4 = (t & 15) * 4;
        float4 v = *(const float4*)&xb[(size_t)cl * N_SP + n4];
        float s = sw[cl], o = sb[cl];
        tile[cl][n4 + 0] = v.x * s + o;
        tile[cl][n4 + 1] = v.y * s + o;
        tile[cl][n4 + 2] = v.z * s + o;
        tile[cl][n4 + 3] = v.w * s + o;
    }
    __syncthreads();
    __bf16* hb = hT + ((size_t)bb * N_SP + bn) * C_DIM + bc;
    int nl = t >> 2, c16 = (t & 3) * 16;
    bf16x8 o1, o2;
#pragma unroll
    for (int e = 0; e < 8; ++e) o1[e] = (__bf16)tile[c16 + e][nl];
#pragma unroll
    for (int e = 0; e < 8; ++e) o2[e] = (__bf16)tile[c16 + 8 + e][nl];
    *(bf16x8*)&hb[(size_t)nl * C_DIM + c16] = o1;
    *(bf16x8*)&hb[(size_t)nl * C_DIM + c16 + 8] = o2;
}

// ---------------- fp32 -> bf16 weight conversion ----------------
__global__ __launch_bounds__(256) void f2bf_kernel(const float* __restrict__ in,
                                                   __bf16* __restrict__ out) {
    int i = blockIdx.x * 256 + threadIdx.x;
    float4 v = ((const float4*)in)[i];
    bf16x4 o;
    o[0] = (__bf16)v.x; o[1] = (__bf16)v.y; o[2] = (__bf16)v.z; o[3] = (__bf16)v.w;
    ((bf16x4*)out)[i] = o;
}

// ------- softmax over row of 1024 fp32, write bf16 P packed in-place -------
__global__ __launch_bounds__(256) void softmax_kernel(float* __restrict__ S) {
    float* p = S + (size_t)blockIdx.x * N_SP;
    int tid = threadIdx.x;
    float4 v = ((float4*)p)[tid];
    float m = fmaxf(fmaxf(v.x, v.y), fmaxf(v.z, v.w));
    for (int off = 32; off > 0; off >>= 1) m = fmaxf(m, __shfl_xor(m, off));
    __shared__ float lm[4], lsum[4];
    int wid = tid >> 6;
    if ((tid & 63) == 0) lm[wid] = m;
    __syncthreads();
    m = fmaxf(fmaxf(lm[0], lm[1]), fmaxf(lm[2], lm[3]));
    v.x = __expf(v.x - m); v.y = __expf(v.y - m);
    v.z = __expf(v.z - m); v.w = __expf(v.w - m);
    float s = v.x + v.y + v.z + v.w;
    for (int off = 32; off > 0; off >>= 1) s += __shfl_xor(s, off);
    if ((tid & 63) == 0) lsum[wid] = s;
    __syncthreads();
    s = lsum[0] + lsum[1] + lsum[2] + lsum[3];
    float inv = 1.f / s;
    bf16x4 o;
    o[0] = (__bf16)(v.x * inv); o[1] = (__bf16)(v.y * inv);
    o[2] = (__bf16)(v.z * inv); o[3] = (__bf16)(v.w * inv);
    __syncthreads();                 // all float4 reads of this row are done
    ((bf16x4*)p)[tid] = o;           // first 2048 bytes of the 4096B row
}

// ======================= 256x256 8-wave deep-pipelined GEMM =======================
// C[M][N] = A[M][LDA-rows] * BT[N][LDB-rows]^T, bf16 in, fp32 acc.
// 4 phases per K-tile (BK=64); per phase: stage 1 unit (2 gload_lds) + 1 C-quadrant
// (16 MFMA); counted vmcnt(4); raw barriers; XOR k-slot swizzle; XCD-chunked grid.
// EPI: 0 bf16; 1 bf16+bias[col]; 2 bf16+bias[row]; 3 f32*scale; 4 f32+bias[row]+resid
#define WAITV(n) asm volatile("s_waitcnt vmcnt(" #n ")" ::: "memory")
#define BAR() __builtin_amdgcn_s_barrier()

template <int M, int N, int K, int LDA, int LDB, int EPI>
__global__ __launch_bounds__(512, 2) void gemm8p(const __bf16* __restrict__ A, size_t sA,
                                                 const __bf16* __restrict__ BT, size_t sB,
                                                 void* __restrict__ Y, size_t sY,
                                                 const float* __restrict__ bias,
                                                 const float* __restrict__ resid, size_t sR,
                                                 float scale) {
    static_assert(M % 256 == 0 && N % 256 == 0 && K % 128 == 0, "shape");
    constexpr int GX = N / 256, GY = M / 256, NT = K / 64;
    // [buf][op A=0/B=1][256 rows x 64 k]; A rows grouped per unit mh: {wm0 quarter, wm1 quarter};
    // B rows grouped per unit nh: {wn0..wn3 32-row slices}
    __shared__ __align__(16) __bf16 lds[2][2][16384];

    const int tid = threadIdx.x;
    const int w = tid >> 6, lane = tid & 63;
    const int wm = w >> 2, wn = w & 3;
    const int lrow = lane & 15, koct = lane >> 4;

    // bijective XCD-chunked swizzle (all our grids are % 8 == 0)
    const int nwg = gridDim.x;
    const int wg = ((int)blockIdx.x & 7) * (nwg >> 3) + ((int)blockIdx.x >> 3);
    const int bz = wg / (GX * GY);
    const int rem = wg - bz * (GX * GY);
    const int bm = (rem / GX) * 256, bn = (rem % GX) * 256;

    const __bf16* Ab = A + (size_t)bz * sA;
    const __bf16* Bb = BT + (size_t)bz * sB;

    // ---- staging addressing: thread covers chunk tid (s=0) and tid+512 (s=1)
    const int rr = tid >> 3;                               // unit-row for s=0, +64 for s=1
    const int kSwz = ((tid & 7) ^ (rr & 7)) * 8;           // pre-swizzled global k offset
    const __bf16* srcA = Ab + (size_t)(bm + rr) * LDA + kSwz;
    const __bf16* srcB = Bb + (size_t)(bn + ((rr >> 5) << 6) + (rr & 31)) * LDB + kSwz;
    const int dstOff = w * 512;                            // elements

#define STG_A(buf, MH, KT) do { \
    gload16(srcA + (size_t)((MH) * 64) * LDA + (KT) * 64,        &lds[buf][0][(MH) * 8192 + dstOff]); \
    gload16(srcA + (size_t)((MH) * 64 + 128) * LDA + (KT) * 64,  &lds[buf][0][(MH) * 8192 + 4096 + dstOff]); \
} while (0)
#define STG_B(buf, NH, KT) do { \
    gload16(srcB + (size_t)((NH) * 32) * LDB + (KT) * 64,        &lds[buf][1][(NH) * 8192 + dstOff]); \
    gload16(srcB + (size_t)((NH) * 32 + 128) * LDB + (KT) * 64,  &lds[buf][1][(NH) * 8192 + 4096 + dstOff]); \
} while (0)

    // ---- fragment read addressing (swizzled k slots; 2-way max bank alias)
    const int ks0 = ((koct ^ (lrow & 7)) * 8);
    const int ks1 = ks0 ^ 32;
    const int arow = (wm * 64 + lrow) * 64;
    const int brow = (wn * 32 + lrow) * 64;

    f32x4 acc[2][2][4][2];
#pragma unroll
    for (int a_ = 0; a_ < 2; ++a_)
#pragma unroll
        for (int b_ = 0; b_ < 2; ++b_)
#pragma unroll
            for (int c_ = 0; c_ < 4; ++c_)
#pragma unroll
                for (int d_ = 0; d_ < 2; ++d_) acc[a_][b_][c_][d_] = (f32x4){0.f, 0.f, 0.f, 0.f};

#define MFMA_(a, b, c) c = __builtin_amdgcn_mfma_f32_16x16x32_bf16(a, b, c, 0, 0, 0)
#define COMPUTE(buf, MH, NH) do { \
    const __bf16* pa = &lds[buf][0][(MH) * 8192 + arow]; \
    const __bf16* pb = &lds[buf][1][(NH) * 8192 + brow]; \
    bf16x8 a00 = *(const bf16x8*)(pa + ks0); \
    bf16x8 a01 = *(const bf16x8*)(pa + 1024 + ks0); \
    bf16x8 a02 = *(const bf16x8*)(pa + 2048 + ks0); \
    bf16x8 a03 = *(const bf16x8*)(pa + 3072 + ks0); \
    bf16x8 a10 = *(const bf16x8*)(pa + ks1); \
    bf16x8 a11 = *(const bf16x8*)(pa + 1024 + ks1); \
    bf16x8 a12 = *(const bf16x8*)(pa + 2048 + ks1); \
    bf16x8 a13 = *(const bf16x8*)(pa + 3072 + ks1); \
    bf16x8 b00 = *(const bf16x8*)(pb + ks0); \
    bf16x8 b01 = *(const bf16x8*)(pb + 1024 + ks0); \
    bf16x8 b10 = *(const bf16x8*)(pb + ks1); \
    bf16x8 b11 = *(const bf16x8*)(pb + 1024 + ks1); \
    __builtin_amdgcn_s_setprio(1); \
    MFMA_(a00, b00, acc[MH][NH][0][0]); MFMA_(a01, b00, acc[MH][NH][1][0]); \
    MFMA_(a02, b00, acc[MH][NH][2][0]); MFMA_(a03, b00, acc[MH][NH][3][0]); \
    MFMA_(a00, b01, acc[MH][NH][0][1]); MFMA_(a01, b01, acc[MH][NH][1][1]); \
    MFMA_(a02, b01, acc[MH][NH][2][1]); MFMA_(a03, b01, acc[MH][NH][3][1]); \
    MFMA_(a10, b10, acc[MH][NH][0][0]); MFMA_(a11, b10, acc[MH][NH][1][0]); \
    MFMA_(a12, b10, acc[MH][NH][2][0]); MFMA_(a13, b10, acc[MH][NH][3][0]); \
    MFMA_(a10, b11, acc[MH][NH][0][1]); MFMA_(a11, b11, acc[MH][NH][1][1]); \
    MFMA_(a12, b11, acc[MH][NH][2][1]); MFMA_(a13, b11, acc[MH][NH][3][1]); \
    __builtin_amdgcn_s_setprio(0); \
} while (0)

    // prologue: tile 0 -> buf0, deadline order [A0, B0, B1, A1]; leave B1,A1 in flight
    STG_A(0, 0, 0); STG_B(0, 0, 0); STG_B(0, 1, 0); STG_A(0, 1, 0);
    WAITV(4); BAR();

#pragma unroll 1
    for (int t = 0; t < NT - 1; ++t) {
        const int cb = t & 1, pf = cb ^ 1;
        const int kt = t + 1;
        STG_A(pf, 0, kt); COMPUTE(cb, 0, 0); WAITV(4); BAR();   // retire B1(t)
        STG_B(pf, 0, kt); COMPUTE(cb, 0, 1); WAITV(4); BAR();   // retire A1(t)
        STG_B(pf, 1, kt); COMPUTE(cb, 1, 0); BAR();
        STG_A(pf, 1, kt); COMPUTE(cb, 1, 1); WAITV(4); BAR();   // retire A0,B0(t+1)
    }
    {   // tail tile (no staging)
        const int cb = (NT - 1) & 1;
        COMPUTE(cb, 0, 0); WAITV(2); BAR();
        COMPUTE(cb, 0, 1); WAITV(0); BAR();
        COMPUTE(cb, 1, 0); BAR();
        COMPUTE(cb, 1, 1);
    }

    // ---- epilogue: C/D frag layout col=lane&15, row=koct*4+reg
    const int lr4 = koct * 4;
    float* Yf = (float*)Y + (size_t)bz * sY;
    __bf16* Yh = (__bf16*)Y + (size_t)bz * sY;
    const float* Rb = (EPI == 4) ? (resid + (size_t)bz * sR) : nullptr;
#pragma unroll
    for (int mh = 0; mh < 2; ++mh)
#pragma unroll
        for (int i = 0; i < 4; ++i)
#pragma unroll
            for (int r = 0; r < 4; ++r) {
                int grow = bm + wm * 128 + mh * 64 + i * 16 + lr4 + r;
                float brv = (EPI == 2 || EPI == 4) ? bias[grow] : 0.f;
#pragma unroll
                for (int nh = 0; nh < 2; ++nh)
#pragma unroll
                    for (int j = 0; j < 2; ++j) {
                        int gcol = bn + wn * 64 + nh * 32 + j * 16 + lrow;
                        float vv = acc[mh][nh][i][j][r];
                        if (EPI == 1) vv += bias[gcol];
                        if (EPI == 2 || EPI == 4) vv += brv;
                        if (EPI == 3) vv *= scale;
                        size_t yi = (size_t)grow * N + gcol;
                        if (EPI == 3 || EPI == 4) {
                            if (EPI == 4) vv += Rb[yi];
                            Yf[yi] = vv;
                        } else {
                            Yh[yi] = (__bf16)vv;
                        }
                    }
            }
#undef STG_A
#undef STG_B
#undef COMPUTE
#undef MFMA_
}

extern "C" void kernel_launch(void* const* d_in, const int* in_sizes, int n_in,
                              void* d_out, int out_size, void* d_ws, size_t ws_size,
                              hipStream_t stream) {
    const float* x      = (const float*)d_in[0];
    const float* norm_w = (const float*)d_in[1];
    const float* norm_b = (const float*)d_in[2];
    const float* q_w    = (const float*)d_in[3];
    const float* q_b    = (const float*)d_in[4];
    const float* k_w    = (const float*)d_in[5];
    const float* k_b    = (const float*)d_in[6];
    const float* v_w    = (const float*)d_in[7];
    const float* v_b    = (const float*)d_in[8];
    const float* proj_w = (const float*)d_in[9];
    const float* proj_b = (const float*)d_in[10];
    float* out = (float*)d_out;

    const size_t ELEM = (size_t)N_SP * C_DIM;          // 524288
    char* ws = (char*)d_ws;
    __bf16* hT = (__bf16*)ws;                          // 32MB; reused as Ot
    __bf16* qT = (__bf16*)(ws + ((size_t)32 << 20));   // 32MB
    __bf16* kT = (__bf16*)(ws + ((size_t)64 << 20));   // 32MB
    __bf16* wq = (__bf16*)(ws + ((size_t)96 << 20));
    __bf16* wk = wq + 262144;
    __bf16* wv = wk + 262144;
    __bf16* wp = wv + 262144;
    float* stats = (float*)(ws + ((size_t)98 << 20));
    size_t sbase = ((size_t)98 << 20) + 65536;
    float* S = (float*)(ws + sbase);
    __bf16* v  = (__bf16*)d_out;                       // V lives in d_out until proj
    __bf16* Ot = hT;                                   // hT dead after v GEMM

    int chunk = (int)((ws_size - sbase) >> 22);        // 4MB per batch of S
    if (chunk > B_DIM) chunk = B_DIM;
    if (chunk < 1) chunk = 1;

    gn_stats_kernel<<<B_DIM * GROUPS, 256, 0, stream>>>(x, stats);
    gn_apply_t_kernel<<<dim3(16, 8, B_DIM), 256, 0, stream>>>(x, stats, norm_w, norm_b, hT);

    f2bf_kernel<<<256, 256, 0, stream>>>(q_w, wq);
    f2bf_kernel<<<256, 256, 0, stream>>>(k_w, wk);
    f2bf_kernel<<<256, 256, 0, stream>>>(v_w, wv);
    f2bf_kernel<<<256, 256, 0, stream>>>(proj_w, wp);

    // qT[n][oc] = sum_c hT[n][c] * wq[oc][c] + q_b[oc]
    gemm8p<1024, 512, 512, 512, 512, 1><<<256, 512, 0, stream>>>(
        hT, ELEM, wq, 0, qT, ELEM, q_b, nullptr, 0, 1.f);
    gemm8p<1024, 512, 512, 512, 512, 1><<<256, 512, 0, stream>>>(
        hT, ELEM, wk, 0, kT, ELEM, k_b, nullptr, 0, 1.f);
    // v[oc][n] = sum_c wv[oc][c] * hT[n][c] + v_b[oc]
    gemm8p<512, 1024, 512, 512, 512, 2><<<256, 512, 0, stream>>>(
        wv, 0, hT, ELEM, v, ELEM, v_b, nullptr, 0, 1.f);

    const float scale = 0.044194173824159216f;  // 512^-0.5
    for (int b0 = 0; b0 < B_DIM; b0 += chunk) {
        int nb = (b0 + chunk <= B_DIM) ? chunk : (B_DIM - b0);
        // S[i][j] = scale * sum_c qT[i][c] kT[j][c]
        gemm8p<1024, 1024, 512, 512, 512, 3><<<16 * nb, 512, 0, stream>>>(
            qT + (size_t)b0 * ELEM, ELEM, kT + (size_t)b0 * ELEM, ELEM,
            S, (size_t)N_SP * N_SP, nullptr, nullptr, 0, scale);
        softmax_kernel<<<nb * N_SP, 256, 0, stream>>>(S);
        // Ot[i][c] = sum_j P[i][j] v[c][j]   (P packed bf16 in S rows, ld 2048)
        gemm8p<1024, 512, 1024, 2048, 1024, 0><<<8 * nb, 512, 0, stream>>>(
            (const __bf16*)S, (size_t)N_SP * 2048, v + (size_t)b0 * ELEM, ELEM,
            Ot + (size_t)b0 * ELEM, ELEM, nullptr, nullptr, 0, 1.f);
    }

    // out[oc][n] = sum_c wp[oc][c] Ot[n][c] + proj_b[oc] + x[oc][n]
    gemm8p<512, 1024, 512, 512, 512, 4><<<256, 512, 0, stream>>>(
        wp, 0, Ot, ELEM, out, ELEM, proj_b, x, ELEM, 1.f);
}

// Round 4
// 256.588 us; speedup vs baseline: 9.1824x; 1.1200x over previous
//
#include <hip/hip_runtime.h>
#include <cstdint>

#define B_DIM 32
#define C_DIM 512
#define N_SP 1024
#define GROUPS 32
#define CPG 16
#define EPS 1e-5f

typedef __attribute__((ext_vector_type(8))) __bf16 bf16x8;
typedef __attribute__((ext_vector_type(4))) __bf16 bf16x4;
typedef __attribute__((ext_vector_type(4))) float f32x4;

__device__ __forceinline__ void gload16(const void* g, void* l) {
    __builtin_amdgcn_global_load_lds(
        (__attribute__((address_space(1))) void*)(unsigned long long)(uintptr_t)g,
        (__attribute__((address_space(3))) void*)(unsigned int)(uintptr_t)l,
        16, 0, 0);
}

// ---------------- GroupNorm stats ----------------
__global__ __launch_bounds__(256) void gn_stats_kernel(const float* __restrict__ x,
                                                       float* __restrict__ stats) {
    int bg = blockIdx.x;
    const float4* p4 = (const float4*)(x + (size_t)bg * (CPG * N_SP));
    int tid = threadIdx.x;
    float s = 0.f, sq = 0.f;
    for (int i = tid; i < (CPG * N_SP) / 4; i += 256) {
        float4 v = p4[i];
        s  += v.x + v.y + v.z + v.w;
        sq += v.x * v.x + v.y * v.y + v.z * v.z + v.w * v.w;
    }
    for (int off = 32; off > 0; off >>= 1) {
        s  += __shfl_xor(s, off);
        sq += __shfl_xor(sq, off);
    }
    __shared__ float ls[4], lq[4];
    int wid = tid >> 6;
    if ((tid & 63) == 0) { ls[wid] = s; lq[wid] = sq; }
    __syncthreads();
    if (tid == 0) {
        s  = ls[0] + ls[1] + ls[2] + ls[3];
        sq = lq[0] + lq[1] + lq[2] + lq[3];
        float mean = s / (float)(CPG * N_SP);
        float var  = sq / (float)(CPG * N_SP) - mean * mean;
        stats[2 * bg]     = mean;
        stats[2 * bg + 1] = rsqrtf(var + EPS);
    }
}

// ------- GroupNorm apply + transpose: x[b][c][n] -> hT[b][n][c] (bf16) -------
__global__ __launch_bounds__(256) void gn_apply_t_kernel(const float* __restrict__ x,
                                                         const float* __restrict__ stats,
                                                         const float* __restrict__ w,
                                                         const float* __restrict__ b,
                                                         __bf16* __restrict__ hT) {
    int bn = blockIdx.x * 64, bc = blockIdx.y * 64, bb = blockIdx.z;
    __shared__ float tile[64][65];
    __shared__ float sw[64], sb[64];
    int t = threadIdx.x;
    if (t < 64) {
        int c = bc + t;
        int g = c / CPG;
        float mean = stats[2 * (bb * GROUPS + g)];
        float rstd = stats[2 * (bb * GROUPS + g) + 1];
        float s = w[c] * rstd;
        sw[t] = s;
        sb[t] = b[c] - mean * s;
    }
    __syncthreads();
    const float* xb = x + ((size_t)bb * C_DIM + bc) * N_SP + bn;
#pragma unroll
    for (int it = 0; it < 4; ++it) {
        int cl = (t >> 4) + 16 * it;
        int n4 = (t & 15) * 4;
        float4 v = *(const float4*)&xb[(size_t)cl * N_SP + n4];
        float s = sw[cl], o = sb[cl];
        tile[cl][n4 + 0] = v.x * s + o;
        tile[cl][n4 + 1] = v.y * s + o;
        tile[cl][n4 + 2] = v.z * s + o;
        tile[cl][n4 + 3] = v.w * s + o;
    }
    __syncthreads();
    __bf16* hb = hT + ((size_t)bb * N_SP + bn) * C_DIM + bc;
    int nl = t >> 2, c16 = (t & 3) * 16;
    bf16x8 o1, o2;
#pragma unroll
    for (int e = 0; e < 8; ++e) o1[e] = (__bf16)tile[c16 + e][nl];
#pragma unroll
    for (int e = 0; e < 8; ++e) o2[e] = (__bf16)tile[c16 + 8 + e][nl];
    *(bf16x8*)&hb[(size_t)nl * C_DIM + c16] = o1;
    *(bf16x8*)&hb[(size_t)nl * C_DIM + c16 + 8] = o2;
}

// ---------------- fp32 -> bf16 conversion (256 blocks x 1024 elems) ----------------
__global__ __launch_bounds__(256) void f2bf_kernel(const float* __restrict__ in,
                                                   __bf16* __restrict__ out) {
    int i = blockIdx.x * 256 + threadIdx.x;
    float4 v = ((const float4*)in)[i];
    bf16x4 o;
    o[0] = (__bf16)v.x; o[1] = (__bf16)v.y; o[2] = (__bf16)v.z; o[3] = (__bf16)v.w;
    ((bf16x4*)out)[i] = o;
}

__global__ __launch_bounds__(256) void pack_qk_bias(const float* __restrict__ qb,
                                                    const float* __restrict__ kb,
                                                    float* __restrict__ o) {
    int i = blockIdx.x * 256 + threadIdx.x;
    o[i] = (i < 512) ? qb[i] : kb[i - 512];
}

// ------- softmax over row of 1024 bf16, in place -------
__global__ __launch_bounds__(256) void softmax_bf16(__bf16* __restrict__ S) {
    __bf16* p = S + (size_t)blockIdx.x * N_SP;
    int tid = threadIdx.x;
    bf16x4 v4 = ((bf16x4*)p)[tid];
    float a = (float)v4[0], b = (float)v4[1], c = (float)v4[2], d = (float)v4[3];
    float m = fmaxf(fmaxf(a, b), fmaxf(c, d));
    for (int off = 32; off > 0; off >>= 1) m = fmaxf(m, __shfl_xor(m, off));
    __shared__ float lm[4], lsum[4];
    int wid = tid >> 6;
    if ((tid & 63) == 0) lm[wid] = m;
    __syncthreads();
    m = fmaxf(fmaxf(lm[0], lm[1]), fmaxf(lm[2], lm[3]));
    a = __expf(a - m); b = __expf(b - m); c = __expf(c - m); d = __expf(d - m);
    float s = a + b + c + d;
    for (int off = 32; off > 0; off >>= 1) s += __shfl_xor(s, off);
    if ((tid & 63) == 0) lsum[wid] = s;
    __syncthreads();
    s = lsum[0] + lsum[1] + lsum[2] + lsum[3];
    float inv = 1.f / s;
    bf16x4 o;
    o[0] = (__bf16)(a * inv); o[1] = (__bf16)(b * inv);
    o[2] = (__bf16)(c * inv); o[3] = (__bf16)(d * inv);
    ((bf16x4*)p)[tid] = o;
}

// ======================= 256x256 8-wave GEMM, register-frag K-tile =======================
// C[M][N] = A[M][*] * BT[N][*]^T, bf16 in, fp32 acc. BK=64; per tile 3 phases:
// {stageA + 12 reads -> Q00}, {stageB + 4 reads -> Q01}, {8 reads -> Q11,Q10 + vmcnt drain}.
// Frags held in regs (<=12 live), XOR k-slot swizzle, XCD-chunked grid, setprio on MFMA.
// EPI: 0 bf16; 1 bf16+bias[col]; 2 bf16+bias[row]; 4 f32+bias[row]+resid; 5 bf16*scale
#define WAITV(n) asm volatile("s_waitcnt vmcnt(" #n ")" ::: "memory")
#define BAR() __builtin_amdgcn_s_barrier()

template <int M, int N, int K, int LDA, int LDB, int EPI>
__global__ __launch_bounds__(512, 2) void gemm8p(const __bf16* __restrict__ A, size_t sA,
                                                 const __bf16* __restrict__ BT, size_t sB,
                                                 void* __restrict__ Y, size_t sY,
                                                 const float* __restrict__ bias,
                                                 const float* __restrict__ resid, size_t sR,
                                                 float scale) {
    static_assert(M % 256 == 0 && N % 256 == 0 && K % 128 == 0, "shape");
    constexpr int GX = N / 256, GY = M / 256, NT = K / 64;
    __shared__ __align__(16) __bf16 lds[2][2][16384];   // [buf][A/B][256 rows x 64 k]

    const int tid = threadIdx.x;
    const int w = tid >> 6, lane = tid & 63;
    const int wm = w >> 2, wn = w & 3;
    const int lrow = lane & 15, koct = lane >> 4;

    const int nwg = gridDim.x;
    const int wg = ((int)blockIdx.x & 7) * (nwg >> 3) + ((int)blockIdx.x >> 3);
    const int bz = wg / (GX * GY);
    const int rem = wg - bz * (GX * GY);
    const int bm = (rem / GX) * 256, bn = (rem % GX) * 256;

    const __bf16* Ab = A + (size_t)bz * sA;
    const __bf16* Bb = BT + (size_t)bz * sB;

    // staging: row srow & srow+64 per gload-pair, source k pre-swizzled, LDS dest linear
    const int srow = tid >> 3;
    const int kswz = ((tid & 7) ^ (srow & 7)) * 8;
    const __bf16* srcA = Ab + (size_t)(bm + srow) * LDA + kswz;
    const __bf16* srcB = Bb + (size_t)(bn + srow) * LDB + kswz;

#define STG_A(buf, half, kt) do { \
    gload16(srcA + (size_t)((half) * 128) * LDA + (size_t)(kt) * 64,      &lds[buf][0][(half) * 8192 + w * 512]); \
    gload16(srcA + (size_t)((half) * 128 + 64) * LDA + (size_t)(kt) * 64, &lds[buf][0][(half) * 8192 + 4096 + w * 512]); \
} while (0)
#define STG_B(buf, half, kt) do { \
    gload16(srcB + (size_t)((half) * 128) * LDB + (size_t)(kt) * 64,      &lds[buf][1][(half) * 8192 + w * 512]); \
    gload16(srcB + (size_t)((half) * 128 + 64) * LDB + (size_t)(kt) * 64, &lds[buf][1][(half) * 8192 + 4096 + w * 512]); \
} while (0)

    // fragment read addressing (swizzled k slots, read side of the involution)
    const int ks0 = (koct ^ (lrow & 7)) * 8;
    const int ks1 = ks0 ^ 32;
    const int abase = (wm * 128 + lrow) * 64;
    const int bbase = (wn * 64 + lrow) * 64;

    bf16x8 aF[4][2], bF[4][2];
    f32x4 acc[8][4];
#pragma unroll
    for (int i = 0; i < 8; ++i)
#pragma unroll
        for (int j = 0; j < 4; ++j) acc[i][j] = (f32x4){0.f, 0.f, 0.f, 0.f};

#define RD_A(ct, i0) do { _Pragma("unroll") for (int i = 0; i < 4; ++i) { \
    aF[i][0] = *(const bf16x8*)&lds[ct][0][abase + ((i0) + i) * 1024 + ks0]; \
    aF[i][1] = *(const bf16x8*)&lds[ct][0][abase + ((i0) + i) * 1024 + ks1]; } } while (0)
#define RD_B(ct, j0) do { _Pragma("unroll") for (int j = 0; j < 2; ++j) { \
    bF[(j0) + j][0] = *(const bf16x8*)&lds[ct][1][bbase + ((j0) + j) * 1024 + ks0]; \
    bF[(j0) + j][1] = *(const bf16x8*)&lds[ct][1][bbase + ((j0) + j) * 1024 + ks1]; } } while (0)

#define MMQ(IH, JH) do { \
    __builtin_amdgcn_s_setprio(1); \
    _Pragma("unroll") for (int k = 0; k < 2; ++k) \
    _Pragma("unroll") for (int i = 0; i < 4; ++i) \
    _Pragma("unroll") for (int j = 0; j < 2; ++j) \
        acc[(IH) * 4 + i][(JH) * 2 + j] = __builtin_amdgcn_mfma_f32_16x16x32_bf16( \
            aF[i][k], bF[(JH) * 2 + j][k], acc[(IH) * 4 + i][(JH) * 2 + j], 0, 0, 0); \
    __builtin_amdgcn_s_setprio(0); \
} while (0)

    // prologue: stage tile 0 fully, drain, barrier
    STG_A(0, 0, 0); STG_A(0, 1, 0); STG_B(0, 0, 0); STG_B(0, 1, 0);
    WAITV(0); BAR();

#pragma unroll 1
    for (int t = 0; t < NT - 1; ++t) {
        const int ct = t & 1, pf = ct ^ 1;
        // P0: stage next-tile A early; read a0-3, b0-1; Q00
        STG_A(pf, 0, t + 1); STG_A(pf, 1, t + 1);
        RD_A(ct, 0); RD_B(ct, 0);
        BAR(); MMQ(0, 0); BAR();
        // P1: stage next-tile B; read b2-3; Q01
        STG_B(pf, 0, t + 1); STG_B(pf, 1, t + 1);
        RD_B(ct, 2);
        BAR(); MMQ(0, 1); BAR();
        // P2: read a4-7; Q11 + Q10; drain own 8 stages (issued >=2 phases ago)
        RD_A(ct, 4);
        BAR(); MMQ(1, 1); MMQ(1, 0);
        WAITV(0); BAR();
    }
    {   // tail tile
        const int ct = (NT - 1) & 1;
        RD_A(ct, 0); RD_B(ct, 0);
        BAR(); MMQ(0, 0); BAR();
        RD_B(ct, 2);
        BAR(); MMQ(0, 1); BAR();
        RD_A(ct, 4);
        BAR(); MMQ(1, 1); MMQ(1, 0);
    }

    // epilogue: C/D layout col=lane&15, row=koct*4+reg
    float* Yf = (float*)Y + (size_t)bz * sY;
    __bf16* Yh = (__bf16*)Y + (size_t)bz * sY;
    const float* Rb = (EPI == 4) ? (resid + (size_t)bz * sR) : nullptr;
#pragma unroll
    for (int i = 0; i < 8; ++i)
#pragma unroll
        for (int r = 0; r < 4; ++r) {
            int grow = bm + wm * 128 + i * 16 + koct * 4 + r;
            float brv = (EPI == 2 || EPI == 4) ? bias[grow] : 0.f;
#pragma unroll
            for (int j = 0; j < 4; ++j) {
                int gcol = bn + wn * 64 + j * 16 + lrow;
                float vv = acc[i][j][r];
                if (EPI == 1) vv += bias[gcol];
                if (EPI == 2 || EPI == 4) vv += brv;
                if (EPI == 5) vv *= scale;
                size_t yi = (size_t)grow * N + gcol;
                if (EPI == 4) {
                    Yf[yi] = vv + Rb[yi];
                } else {
                    Yh[yi] = (__bf16)vv;
                }
            }
        }
#undef STG_A
#undef STG_B
#undef RD_A
#undef RD_B
#undef MMQ
}

extern "C" void kernel_launch(void* const* d_in, const int* in_sizes, int n_in,
                              void* d_out, int out_size, void* d_ws, size_t ws_size,
                              hipStream_t stream) {
    const float* x      = (const float*)d_in[0];
    const float* norm_w = (const float*)d_in[1];
    const float* norm_b = (const float*)d_in[2];
    const float* q_w    = (const float*)d_in[3];
    const float* q_b    = (const float*)d_in[4];
    const float* k_w    = (const float*)d_in[5];
    const float* k_b    = (const float*)d_in[6];
    const float* v_w    = (const float*)d_in[7];
    const float* v_b    = (const float*)d_in[8];
    const float* proj_w = (const float*)d_in[9];
    const float* proj_b = (const float*)d_in[10];
    float* out = (float*)d_out;

    const size_t ELEM = (size_t)N_SP * C_DIM;            // 524288
    const size_t QK   = (size_t)N_SP * 1024;             // 1048576
    char* ws = (char*)d_ws;
    __bf16* hT  = (__bf16*)ws;                           // 32MB, reused as Ot
    __bf16* qkT = (__bf16*)(ws + ((size_t)32 << 20));    // 64MB: [b][n][q||k]
    __bf16* wqk = (__bf16*)(ws + ((size_t)96 << 20));    // 1MB  [1024][512]
    __bf16* wv  = (__bf16*)(ws + ((size_t)97 << 20));
    __bf16* wp  = wv + 262144;
    float* qkb  = (float*)(ws + ((size_t)98 << 20));
    float* stats = qkb + 1024;
    size_t sbase = ((size_t)99 << 20);
    __bf16* S = (__bf16*)(ws + sbase);                   // chunk x [1024][1024] bf16
    __bf16* v  = (__bf16*)d_out;                         // V lives in d_out until proj
    __bf16* Ot = hT;

    int chunk = (int)((ws_size - sbase) >> 21);          // 2MB per batch of S
    if (chunk > B_DIM) chunk = B_DIM;
    if (chunk < 1) chunk = 1;

    gn_stats_kernel<<<B_DIM * GROUPS, 256, 0, stream>>>(x, stats);
    gn_apply_t_kernel<<<dim3(16, 8, B_DIM), 256, 0, stream>>>(x, stats, norm_w, norm_b, hT);

    f2bf_kernel<<<256, 256, 0, stream>>>(q_w, wqk);
    f2bf_kernel<<<256, 256, 0, stream>>>(k_w, wqk + 262144);
    f2bf_kernel<<<256, 256, 0, stream>>>(v_w, wv);
    f2bf_kernel<<<256, 256, 0, stream>>>(proj_w, wp);
    pack_qk_bias<<<4, 256, 0, stream>>>(q_b, k_b, qkb);

    // qkT[n][0..1023] = hT[n][:] x (wq||wk)^T + (q_b||k_b)
    gemm8p<1024, 1024, 512, 512, 512, 1><<<512, 512, 0, stream>>>(
        hT, ELEM, wqk, 0, qkT, QK, qkb, nullptr, 0, 1.f);
    // v[oc][n] = wv[oc][:] x hT[n][:] + v_b[oc]
    gemm8p<512, 1024, 512, 512, 512, 2><<<256, 512, 0, stream>>>(
        wv, 0, hT, ELEM, v, ELEM, v_b, nullptr, 0, 1.f);

    const float scale = 0.044194173824159216f;  // 512^-0.5
    for (int b0 = 0; b0 < B_DIM; b0 += chunk) {
        int nb = (b0 + chunk <= B_DIM) ? chunk : (B_DIM - b0);
        // S[i][j] = bf16( scale * sum_c qT[i][c] kT[j][c] )
        gemm8p<1024, 1024, 512, 1024, 1024, 5><<<16 * nb, 512, 0, stream>>>(
            qkT + (size_t)b0 * QK, QK, qkT + (size_t)b0 * QK + 512, QK,
            S, QK, nullptr, nullptr, 0, scale);
        softmax_bf16<<<nb * N_SP, 256, 0, stream>>>(S);
        // Ot[i][c] = sum_j P[i][j] v[c][j]
        gemm8p<1024, 512, 1024, 1024, 1024, 0><<<8 * nb, 512, 0, stream>>>(
            S, QK, v + (size_t)b0 * ELEM, ELEM,
            Ot + (size_t)b0 * ELEM, ELEM, nullptr, nullptr, 0, 1.f);
    }

    // out[oc][n] = wp[oc][:] x Ot[n][:] + proj_b[oc] + x[oc][n]
    gemm8p<512, 1024, 512, 512, 512, 4><<<256, 512, 0, stream>>>(
        wp, 0, Ot, ELEM, out, ELEM, proj_b, x, ELEM, 1.f);
}